// Round 2
// baseline (784.080 us; speedup 1.0000x reference)
//
#include <hip/hip_runtime.h>

typedef unsigned short u16;
typedef unsigned int u32;
typedef __bf16 bf16x8 __attribute__((ext_vector_type(8)));
typedef float f32x4 __attribute__((ext_vector_type(4)));

#define NV0 100000
#define NV1 50000
#define NV2 25000
#define NV3 12500

// workspace offsets (in u16 elements)
enum : long {
  OFF_WB0  = 0,
  OFF_WD1  = 27648,
  OFF_WB1  = 44032,
  OFF_WD2  = 154624,
  OFF_WB2  = 220160,
  OFF_WD3  = 662528,
  OFF_WB3  = 924672,
  OFF_WU2  = 2694144,
  OFF_WU1  = 2792448,
  OFF_WU0  = 2833408,
  OFF_WOUT = 2848768,
  OFF_TA   = 2897920,               // scratch x0a/x1a/x2a/x3a; later aliased by f32 tmp
  OFF_X0   = OFF_TA  + 3200000,
  OFF_X1   = OFF_X0  + 3200000,
  OFF_X2   = OFF_X1  + 3200000,
  OFF_X3   = OFF_X2  + 3200000,
  OFF_U2   = OFF_X3  + 3200000,
  OFF_U1   = OFF_U2  + 6400000,
  OFF_U0S  = OFF_U1  + 6400000,     // 8192*96 bf16
  OFF_END  = OFF_U0S + 786432,      // ~65 MB total
};

__device__ __forceinline__ float b2f(u16 u) {
  union { u32 i; float f; } x; x.i = ((u32)u) << 16; return x.f;
}
__device__ __forceinline__ u16 f2b(float f) {
  union { float f; u32 i; } x; x.f = f;
  u32 r = (x.i + 0x7FFFu + ((x.i >> 16) & 1u)) >> 16;
  return (u16)r;
}
__device__ __forceinline__ void gload16(const u16* g, const u16* l) {
  __builtin_amdgcn_global_load_lds(
      (const __attribute__((address_space(1))) void*)g,
      (__attribute__((address_space(3))) void*)(u16*)l, 16, 0, 0);
}
__device__ __forceinline__ void store_out(u16* p, float v)  { *p = f2b(v); }
__device__ __forceinline__ void store_out(float* p, float v) { *p = v; }

// ---------------- weight transpose prep: f32 W[k][c][o] -> bf16 Wt[k][o][c] ----------------
struct PD { const float* src; u16* dst; int KK, CIN, COUT; };
struct PrepArgs { PD d[11]; };

__global__ __launch_bounds__(256) void prep_k(PrepArgs pa) {
  const PD d = pa.d[blockIdx.y];
  const int cc = d.CIN * d.COUT;
  const int total = d.KK * cc;
  for (int e = blockIdx.x * 256 + threadIdx.x; e < total; e += gridDim.x * 256) {
    int k = e / cc;
    int r = e - k * cc;
    int c = r / d.COUT;
    int o = r - c * d.COUT;
    d.dst[(k * d.COUT + o) * d.CIN + c] = f2b(d.src[e]);
  }
}

// ---------------- stem: f32 [N0,3] gather-conv -> bf16 [N0,32], relu ----------------
__global__ __launch_bounds__(256) void stem_k(const float* __restrict__ feats,
                                              const int* __restrict__ nbr0,
                                              const float* __restrict__ wstem,
                                              u16* __restrict__ out) {
  __shared__ float Wl[27 * 3 * 32];
  const int tid = threadIdx.x;
  for (int i = tid; i < 2592; i += 256) Wl[i] = wstem[i];
  __syncthreads();
  const int n = blockIdx.x * 8 + (tid >> 5);
  const int o = tid & 31;
  if (n >= NV0) return;
  float acc = 0.f;
  const int* nb = nbr0 + n * 27;
  #pragma unroll
  for (int k = 0; k < 27; k++) {
    const int iv = nb[k];
    const float* f = feats + iv * 3;
    acc = fmaf(f[0], Wl[(k * 3 + 0) * 32 + o], acc);
    acc = fmaf(f[1], Wl[(k * 3 + 1) * 32 + o], acc);
    acc = fmaf(f[2], Wl[(k * 3 + 2) * 32 + o], acc);
  }
  out[n * 32 + o] = f2b(fmaxf(acc, 0.f));
}

// ---------------- generic MFMA gather-GEMM (bf16 in, OT out) ----------------
// MODE 0: A(n,kc) = src0[idx0[n*KK + kc/CIN]*CIN + kc%CIN]      (sparse conv)
// MODE 1: kc<CA ? src0[idx0[n]*CA+kc] : src1[n*CB+kc-CA]        (upsample concat)
// MODE 2: s=idx0[n]; kc<CA ? src0[idx1[s]*CA+kc] : src1[s*CB+kc-CA] (seed concat)
// MODE 3: A = src0[n*KCT + kc]                                  (plain)
template <int BM, int BN, int WM, int WN, int COUTF, int KCT, int MODE, int CIN,
          int KK, int CA, bool RES, bool DORELU, typename OT>
__global__ __launch_bounds__(256) void gemm_k(
    const u16* __restrict__ src0, const u16* __restrict__ src1,
    const int* __restrict__ idx0, const int* __restrict__ idx1,
    const u16* __restrict__ wt, const u16* __restrict__ base,
    OT* __restrict__ out, int N) {
  constexpr int NWM = BM / WM, NWN = BN / WN;
  static_assert(NWM * NWN == 4, "4 waves");
  constexpr int MI = WM / 16, NI = WN / 16;
  constexpr int CB = KCT - CA;
  __shared__ u16 As[BM * 32];
  __shared__ u16 Bs[BN * 32];
  const int tid = threadIdx.x;
  const int w = tid >> 6, lane = tid & 63;
  const int quad = lane >> 4, l16 = lane & 15;
  const int wm = w % NWM, wn = w / NWM;
  const int row0 = blockIdx.x * BM;
  const int col0 = blockIdx.y * BN;
  const int Nm1 = N - 1;

  f32x4 acc[MI][NI];
  #pragma unroll
  for (int i = 0; i < MI; i++)
    #pragma unroll
    for (int j = 0; j < NI; j++) acc[i][j] = {0.f, 0.f, 0.f, 0.f};

  #pragma unroll 1
  for (int kc0 = 0; kc0 < KCT; kc0 += 32) {
    // ---- stage A tile [BM x 32] : wave-chunks of 1KB (16 rows) ----
    for (int jc = w; jc < BM / 16; jc += 4) {
      const int e = jc * 512 + lane * 8;    // u16 index in As
      const int r = e >> 5, co = e & 31;
      int n = row0 + r; n = (n > Nm1) ? Nm1 : n;
      const u16* gp;
      if constexpr (MODE == 0) {
        const int k = kc0 / CIN;
        gp = src0 + idx0[n * KK + k] * CIN + (kc0 & (CIN - 1)) + co;
      } else if constexpr (MODE == 1) {
        if (kc0 < CA) gp = src0 + idx0[n] * CA + kc0 + co;
        else          gp = src1 + n * CB + (kc0 - CA) + co;
      } else if constexpr (MODE == 2) {
        const int s = idx0[n];
        if (kc0 < CA) gp = src0 + idx1[s] * CA + kc0 + co;
        else          gp = src1 + s * CB + (kc0 - CA) + co;
      } else {
        gp = src0 + n * KCT + kc0 + co;
      }
      gload16(gp, &As[jc * 512]);
    }
    // ---- stage B^T tile [BN x 32] from Wt ----
    for (int jc = w; jc < BN / 16; jc += 4) {
      const int e = jc * 512 + lane * 8;
      const int ol = e >> 5, co = e & 31;
      const int o = col0 + ol;
      const u16* gp;
      if constexpr (MODE == 0) {
        const int k = kc0 / CIN;
        gp = wt + (k * COUTF + o) * CIN + (kc0 & (CIN - 1)) + co;
      } else {
        gp = wt + o * KCT + kc0 + co;
      }
      gload16(gp, &Bs[jc * 512]);
    }
    __syncthreads();

    bf16x8 af[MI], bfr[NI];
    #pragma unroll
    for (int i = 0; i < MI; i++)
      af[i] = *(const bf16x8*)&As[(wm * WM + i * 16 + l16) * 32 + quad * 8];
    #pragma unroll
    for (int j = 0; j < NI; j++)
      bfr[j] = *(const bf16x8*)&Bs[(wn * WN + j * 16 + l16) * 32 + quad * 8];
    #pragma unroll
    for (int i = 0; i < MI; i++)
      #pragma unroll
      for (int j = 0; j < NI; j++)
        acc[i][j] = __builtin_amdgcn_mfma_f32_16x16x32_bf16(af[i], bfr[j], acc[i][j], 0, 0, 0);
    __syncthreads();
  }

  // ---- epilogue: C/D layout col=lane&15, row=quad*4+reg ----
  #pragma unroll
  for (int i = 0; i < MI; i++) {
    #pragma unroll
    for (int j = 0; j < NI; j++) {
      const int col = col0 + wn * WN + j * 16 + l16;
      #pragma unroll
      for (int r = 0; r < 4; r++) {
        const int n = row0 + wm * WM + i * 16 + quad * 4 + r;
        if (n < N) {
          float v = acc[i][j][r];
          if constexpr (RES)         v = b2f(base[n * COUTF + col]) + fmaxf(v, 0.f);
          else if constexpr (DORELU) v = fmaxf(v, 0.f);
          store_out(&out[(long)n * COUTF + col], v);
        }
      }
    }
  }
}

// ---------------- final transpose f32 tmp[8192][512] -> f32 out[8][512][1024] ----------------
__global__ __launch_bounds__(256) void tout_k(const float* __restrict__ tmp,
                                              float* __restrict__ outp) {
  __shared__ float tl[64][65];
  const int tid = threadIdx.x;
  const int r0 = blockIdx.x * 64, o0 = blockIdx.y * 64;
  {
    const int rl = tid >> 2, oc = (tid & 3) * 16;
    const float* src = &tmp[(r0 + rl) * 512 + o0 + oc];
    #pragma unroll
    for (int j = 0; j < 16; j++) tl[rl][oc + j] = src[j];
  }
  __syncthreads();
  {
    const int ol = tid >> 2, sc = (tid & 3) * 16;
    const int b = r0 >> 10, s0 = r0 & 1023;
    float* dst = &outp[((long)b * 512 + (o0 + ol)) * 1024 + s0 + sc];
    #pragma unroll
    for (int j = 0; j < 16; j++) dst[j] = tl[sc + j][ol];
  }
}

extern "C" void kernel_launch(void* const* d_in, const int* in_sizes, int n_in,
                              void* d_out, int out_size, void* d_ws, size_t ws_size,
                              hipStream_t stream) {
  const float* feats = (const float*)d_in[0];
  const int* nbr0  = (const int*)d_in[1];
  const int* nbr1  = (const int*)d_in[2];
  const int* nbr2  = (const int*)d_in[3];
  const int* nbr3  = (const int*)d_in[4];
  const int* down1 = (const int*)d_in[5];
  const int* down2 = (const int*)d_in[6];
  const int* down3 = (const int*)d_in[7];
  const int* up2   = (const int*)d_in[8];
  const int* up1   = (const int*)d_in[9];
  const int* up0   = (const int*)d_in[10];
  const int* seed  = (const int*)d_in[11];
  u16* ws = (u16*)d_ws;

  // ---- transpose all f32 weights to bf16 [k][cout][cin] / [cout][kc] ----
  PrepArgs pa;
  pa.d[0]  = {(const float*)d_in[13], ws + OFF_WB0,  27, 32, 32};
  pa.d[1]  = {(const float*)d_in[14], ws + OFF_WD1,  8,  32, 64};
  pa.d[2]  = {(const float*)d_in[15], ws + OFF_WB1,  27, 64, 64};
  pa.d[3]  = {(const float*)d_in[16], ws + OFF_WD2,  8,  64, 128};
  pa.d[4]  = {(const float*)d_in[17], ws + OFF_WB2,  27, 128, 128};
  pa.d[5]  = {(const float*)d_in[18], ws + OFF_WD3,  8,  128, 256};
  pa.d[6]  = {(const float*)d_in[19], ws + OFF_WB3,  27, 256, 256};
  pa.d[7]  = {(const float*)d_in[20], ws + OFF_WU2,  1,  384, 256};
  pa.d[8]  = {(const float*)d_in[21], ws + OFF_WU1,  1,  320, 128};
  pa.d[9]  = {(const float*)d_in[22], ws + OFF_WU0,  1,  160, 96};
  pa.d[10] = {(const float*)d_in[23], ws + OFF_WOUT, 1,  96,  512};
  prep_k<<<dim3(128, 11), 256, 0, stream>>>(pa);

  u16* ta  = ws + OFF_TA;
  u16* x0  = ws + OFF_X0;
  u16* x1  = ws + OFF_X1;
  u16* x2  = ws + OFF_X2;
  u16* x3  = ws + OFF_X3;
  u16* u2b = ws + OFF_U2;
  u16* u1b = ws + OFF_U1;
  u16* u0s = ws + OFF_U0S;
  float* tmp = (float*)(ws + OFF_TA);   // aliases TA/X0/X1 (dead by the time s2 runs)

  // stem -> ta (=x0a)
  stem_k<<<12500, 256, 0, stream>>>(feats, nbr0, (const float*)d_in[12], ta);

  // b0: x0 = x0a + relu(conv(x0a, nbr0, W_b0))
  gemm_k<256, 32, 64, 32, 32, 864, 0, 32, 27, 0, true, true, u16>
      <<<dim3(391, 1), 256, 0, stream>>>(ta, nullptr, nbr0, nullptr, ws + OFF_WB0, ta, x0, NV0);
  // d1: x1a = relu(conv(x0, down1, W_d1))
  gemm_k<128, 64, 64, 32, 64, 256, 0, 32, 8, 0, false, true, u16>
      <<<dim3(391, 1), 256, 0, stream>>>(x0, nullptr, down1, nullptr, ws + OFF_WD1, nullptr, ta, NV1);
  // b1
  gemm_k<128, 64, 64, 32, 64, 1728, 0, 64, 27, 0, true, true, u16>
      <<<dim3(391, 1), 256, 0, stream>>>(ta, nullptr, nbr1, nullptr, ws + OFF_WB1, ta, x1, NV1);
  // d2
  gemm_k<128, 128, 64, 64, 128, 512, 0, 64, 8, 0, false, true, u16>
      <<<dim3(196, 1), 256, 0, stream>>>(x1, nullptr, down2, nullptr, ws + OFF_WD2, nullptr, ta, NV2);
  // b2
  gemm_k<128, 128, 64, 64, 128, 3456, 0, 128, 27, 0, true, true, u16>
      <<<dim3(196, 1), 256, 0, stream>>>(ta, nullptr, nbr2, nullptr, ws + OFF_WB2, ta, x2, NV2);
  // d3
  gemm_k<128, 128, 64, 64, 256, 1024, 0, 128, 8, 0, false, true, u16>
      <<<dim3(98, 2), 256, 0, stream>>>(x2, nullptr, down3, nullptr, ws + OFF_WD3, nullptr, ta, NV3);
  // b3
  gemm_k<128, 128, 64, 64, 256, 6912, 0, 256, 27, 0, true, true, u16>
      <<<dim3(98, 2), 256, 0, stream>>>(ta, nullptr, nbr3, nullptr, ws + OFF_WB3, ta, x3, NV3);
  // u2 = relu(cat(x3[up2], x2) @ W_u2)
  gemm_k<128, 128, 64, 64, 256, 384, 1, 32, 1, 256, false, true, u16>
      <<<dim3(196, 2), 256, 0, stream>>>(x3, x2, up2, nullptr, ws + OFF_WU2, nullptr, u2b, NV2);
  // u1 = relu(cat(u2[up1], x1) @ W_u1)
  gemm_k<128, 128, 64, 64, 128, 320, 1, 32, 1, 256, false, true, u16>
      <<<dim3(391, 1), 256, 0, stream>>>(u2b, x1, up1, nullptr, ws + OFF_WU1, nullptr, u1b, NV1);
  // s1: per-seed u0 = relu(cat(u1[up0[seed]], x0[seed]) @ W_u0)  [8192 x 96]
  gemm_k<128, 96, 64, 48, 96, 160, 2, 32, 1, 128, false, true, u16>
      <<<dim3(64, 1), 256, 0, stream>>>(u1b, x0, seed, up0, ws + OFF_WU0, nullptr, u0s, 8192);
  // s2: tmp = u0s @ W_out   [8192 x 512] f32, no relu
  gemm_k<128, 128, 64, 64, 512, 96, 3, 32, 1, 0, false, false, float>
      <<<dim3(64, 4), 256, 0, stream>>>(u0s, nullptr, nullptr, nullptr, ws + OFF_WOUT, nullptr, tmp, 8192);
  // transpose to [B, 512, S] f32
  tout_k<<<dim3(128, 8), 256, 0, stream>>>(tmp, (float*)d_out);
}